// Round 1
// baseline (672.776 us; speedup 1.0000x reference)
//
#include <hip/hip_runtime.h>
#include <hip/hip_bf16.h>
#include <cstdint>

#define NB   128
#define CD   64
#define LD   4096
#define KC   100
#define KP   128
#define LSPLIT 8
#define LS   (LD / LSPLIT)

__device__ __forceinline__ float bf_lo(uint32_t u) { return __uint_as_float(u << 16); }
__device__ __forceinline__ float bf_hi(uint32_t u) { return __uint_as_float(u & 0xffff0000u); }

__device__ __forceinline__ uint32_t pack_bf2(float a, float b) {
    __hip_bfloat16 ha = __float2bfloat16(a), hb = __float2bfloat16(b);
    uint16_t ua = *reinterpret_cast<uint16_t*>(&ha);
    uint16_t ub = *reinterpret_cast<uint16_t*>(&hb);
    return (uint32_t)ua | ((uint32_t)ub << 16);
}

// K1: per-location channel-norm + logits + softmax -> a (bf16) laid out [nn][l][KP]
__global__ __launch_bounds__(128, 1) void k_assign(
    const float* __restrict__ x, const float* __restrict__ w,
    const float* __restrict__ b, __hip_bfloat16* __restrict__ a_t, int n0)
{
    __shared__ float lgt[KC][128];   // 51.2 KB; each thread owns one column -> no barriers
    const int tid = threadIdx.x;
    const int nn  = blockIdx.x >> 5;          // / 32
    const int lb  = (blockIdx.x & 31) << 7;   // * 128
    const int n   = n0 + nn;
    const int l   = lb + tid;

    const float* xp = x + (size_t)n * CD * LD + l;
    float xv[CD];
    float ss = 0.f;
#pragma unroll
    for (int c = 0; c < CD; ++c) {
        xv[c] = xp[(size_t)c * LD];           // coalesced across lanes (consecutive l)
        ss = fmaf(xv[c], xv[c], ss);
    }
    const float rn = 1.0f / fmaxf(sqrtf(ss), 1e-12f);

    for (int k = 0; k < KC; ++k) {
        const float* wr = w + k * CD;         // uniform -> scalar loads
        float d0 = 0.f, d1 = 0.f, d2 = 0.f, d3 = 0.f;
#pragma unroll
        for (int c = 0; c < CD; c += 4) {
            d0 = fmaf(wr[c + 0], xv[c + 0], d0);
            d1 = fmaf(wr[c + 1], xv[c + 1], d1);
            d2 = fmaf(wr[c + 2], xv[c + 2], d2);
            d3 = fmaf(wr[c + 3], xv[c + 3], d3);
        }
        lgt[k][tid] = rn * ((d0 + d1) + (d2 + d3)) + b[k];
    }

    float m = -1e30f;
    for (int k = 0; k < KC; ++k) m = fmaxf(m, lgt[k][tid]);
    float s = 0.f;
    for (int k = 0; k < KC; ++k) {
        float e = __expf(lgt[k][tid] - m);
        lgt[k][tid] = e;
        s += e;
    }
    const float inv = 1.0f / s;

    __hip_bfloat16* ap = a_t + ((size_t)nn * LD + l) * KP;
    for (int kb = 0; kb < 96; kb += 8) {
        uint32_t pk[4];
#pragma unroll
        for (int j = 0; j < 4; ++j)
            pk[j] = pack_bf2(lgt[kb + 2 * j][tid] * inv, lgt[kb + 2 * j + 1][tid] * inv);
        *reinterpret_cast<uint4*>(ap + kb) = *reinterpret_cast<uint4*>(pk);
    }
    {   // tail: k = 96..99 plus zero padding to KP=128
        uint32_t pk[4];
        pk[0] = pack_bf2(lgt[96][tid] * inv, lgt[97][tid] * inv);
        pk[1] = pack_bf2(lgt[98][tid] * inv, lgt[99][tid] * inv);
        pk[2] = 0u; pk[3] = 0u;
        *reinterpret_cast<uint4*>(ap + 96) = *reinterpret_cast<uint4*>(pk);
        uint4 z; z.x = 0u; z.y = 0u; z.z = 0u; z.w = 0u;
        *reinterpret_cast<uint4*>(ap + 104) = z;
        *reinterpret_cast<uint4*>(ap + 112) = z;
        *reinterpret_cast<uint4*>(ap + 120) = z;
    }
}

// K2: agg[k,c] partial sums over one eighth of L, per n. 256 thr, 8k x 4c register tile.
__global__ __launch_bounds__(256, 1) void k_agg(
    const float* __restrict__ x, const __hip_bfloat16* __restrict__ a_t,
    float* __restrict__ agg_p, float* __restrict__ asum_p, int n0)
{
    __shared__ float xt[64][68];             // x tile transposed [l][c], pad->2-way (free)
    __shared__ __hip_bfloat16 al[64][KP];    // a tile [l][k]

    const int tid = threadIdx.x;
    const int ls  = blockIdx.x & (LSPLIT - 1);
    const int nn  = blockIdx.x / LSPLIT;
    const int n   = n0 + nn;
    const int kt  = tid >> 4;
    const int ct  = tid & 15;

    float acc[8][4];
#pragma unroll
    for (int i = 0; i < 8; ++i)
#pragma unroll
        for (int j = 0; j < 4; ++j) acc[i][j] = 0.f;
    float asl = 0.f;

    const int lb0 = ls * LS;
    const float* xbase = x + (size_t)n * CD * LD + lb0;
    const uint4* abase = reinterpret_cast<const uint4*>(a_t + ((size_t)nn * LD + lb0) * KP);

    for (int t = 0; t < LS; t += 64) {
        // stage x tile: read [c][64 l] coalesced, write transposed
#pragma unroll
        for (int i = 0; i < 16; ++i) {
            int idx = tid + (i << 8);
            int cc = idx >> 6, ll = idx & 63;
            xt[ll][cc] = xbase[(size_t)cc * LD + t + ll];
        }
        // stage a tile: 64 rows * 256 B = 1024 uint4
        const uint4* asrc = abase + (size_t)t * (KP / 8);
#pragma unroll
        for (int i = 0; i < 4; ++i)
            reinterpret_cast<uint4*>(&al[0][0])[tid + (i << 8)] = asrc[tid + (i << 8)];
        __syncthreads();

        if (tid < KP) {                      // waves 0-1: accumulate asum[k=tid]
#pragma unroll 8
            for (int ll = 0; ll < 64; ++ll) asl += __bfloat162float(al[ll][tid]);
        }

        for (int ll = 0; ll < 64; ++ll) {
            uint4 au = *reinterpret_cast<const uint4*>(&al[ll][kt << 3]);  // 8 bf16, broadcast groups
            float av[8];
            av[0] = bf_lo(au.x); av[1] = bf_hi(au.x);
            av[2] = bf_lo(au.y); av[3] = bf_hi(au.y);
            av[4] = bf_lo(au.z); av[5] = bf_hi(au.z);
            av[6] = bf_lo(au.w); av[7] = bf_hi(au.w);
            float4 xv4 = *reinterpret_cast<const float4*>(&xt[ll][ct << 2]);
            float xs0 = xv4.x, xs1 = xv4.y, xs2 = xv4.z, xs3 = xv4.w;
#pragma unroll
            for (int i = 0; i < 8; ++i) {
                acc[i][0] = fmaf(av[i], xs0, acc[i][0]);
                acc[i][1] = fmaf(av[i], xs1, acc[i][1]);
                acc[i][2] = fmaf(av[i], xs2, acc[i][2]);
                acc[i][3] = fmaf(av[i], xs3, acc[i][3]);
            }
        }
        __syncthreads();
    }

    float* op = agg_p + (((size_t)nn * LSPLIT + ls) * KP + (kt << 3)) * 64 + (ct << 2);
#pragma unroll
    for (int i = 0; i < 8; ++i) {
        float4 v; v.x = acc[i][0]; v.y = acc[i][1]; v.z = acc[i][2]; v.w = acc[i][3];
        *reinterpret_cast<float4*>(op + (size_t)i * 64) = v;
    }
    if (tid < KP) asum_p[((size_t)nn * LSPLIT + ls) * KP + tid] = asl;
}

// K3: reduce partials, subtract centroid*asum, intra-norm over C, global L2 norm, write out.
__global__ __launch_bounds__(256, 1) void k_final(
    const float* __restrict__ agg_p, const float* __restrict__ asum_p,
    const float* __restrict__ cent, float* __restrict__ out, int n0)
{
    __shared__ float vbuf[KC][65];
    __shared__ float asum_s[KP];
    __shared__ float rn_s[KC];
    __shared__ float red[256];

    const int tid = threadIdx.x;
    const int nn  = blockIdx.x;
    const int n   = n0 + nn;

    if (tid < KP) {
        float s = 0.f;
#pragma unroll
        for (int ls = 0; ls < LSPLIT; ++ls)
            s += asum_p[((size_t)nn * LSPLIT + ls) * KP + tid];
        asum_s[tid] = s;
    }
    __syncthreads();

    for (int idx = tid; idx < KC * CD; idx += 256) {
        int k = idx >> 6, c = idx & 63;
        float s = 0.f;
#pragma unroll
        for (int ls = 0; ls < LSPLIT; ++ls)
            s += agg_p[(((size_t)nn * LSPLIT + ls) * KP + k) * 64 + c];
        vbuf[k][c] = fmaf(-cent[idx], asum_s[k], s);
    }
    __syncthreads();

    if (tid < KC) {
        float ssq = 0.f;
#pragma unroll 8
        for (int c = 0; c < CD; ++c) {
            float v = vbuf[tid][c];
            ssq = fmaf(v, v, ssq);
        }
        rn_s[tid] = 1.0f / fmaxf(sqrtf(ssq), 1e-12f);
    }
    __syncthreads();

    float gp = 0.f;
    for (int idx = tid; idx < KC * CD; idx += 256) {
        int k = idx >> 6, c = idx & 63;
        float v = vbuf[k][c] * rn_s[k];
        gp = fmaf(v, v, gp);
    }
    red[tid] = gp;
    __syncthreads();
    for (int off = 128; off > 0; off >>= 1) {
        if (tid < off) red[tid] += red[tid + off];
        __syncthreads();
    }
    const float g = 1.0f / fmaxf(sqrtf(red[0]), 1e-12f);

    float* op = out + (size_t)n * (KC * CD);
    for (int idx = tid; idx < KC * CD; idx += 256) {
        int k = idx >> 6, c = idx & 63;
        op[idx] = vbuf[k][c] * rn_s[k] * g;
    }
}

extern "C" void kernel_launch(void* const* d_in, const int* in_sizes, int n_in,
                              void* d_out, int out_size, void* d_ws, size_t ws_size,
                              hipStream_t stream)
{
    const float* x  = (const float*)d_in[0];
    const float* w  = (const float*)d_in[1];
    const float* b  = (const float*)d_in[2];
    const float* ct = (const float*)d_in[3];
    float* out = (float*)d_out;

    const size_t a_per_n    = (size_t)LD * KP * 2;          // bf16 assignments
    const size_t agg_per_n  = (size_t)LSPLIT * KP * 64 * 4; // fp32 agg partials
    const size_t asum_per_n = (size_t)LSPLIT * KP * 4;      // fp32 asum partials
    const size_t per_n = a_per_n + agg_per_n + asum_per_n;

    int nc = (int)(ws_size / per_n);
    if (nc < 1) nc = 1;
    if (nc > NB) nc = NB;

    char* wsp = (char*)d_ws;
    __hip_bfloat16* a_t = (__hip_bfloat16*)wsp;
    float* agg_p  = (float*)(wsp + a_per_n * (size_t)nc);
    float* asum_p = (float*)(wsp + (a_per_n + agg_per_n) * (size_t)nc);

    for (int n0 = 0; n0 < NB; n0 += nc) {
        int cn = NB - n0; if (cn > nc) cn = nc;
        k_assign<<<cn * 32, 128, 0, stream>>>(x, w, b, a_t, n0);
        k_agg<<<cn * LSPLIT, 256, 0, stream>>>(x, a_t, agg_p, asum_p, n0);
        k_final<<<cn, 256, 0, stream>>>(agg_p, asum_p, ct, out, n0);
    }
}

// Round 2
// 217.096 us; speedup vs baseline: 3.0990x; 3.0990x over previous
//
#include <hip/hip_runtime.h>
#include <hip/hip_bf16.h>
#include <cstdint>

#define NB   128
#define CD   64
#define LD   4096
#define KC   100
#define KP   128
#define KT   7           // 7 k-tiles of 16 -> 112 padded clusters
#define LSPLIT 8
#define LS   (LD / LSPLIT)

typedef __attribute__((ext_vector_type(8))) short bf16x8;
typedef __attribute__((ext_vector_type(4))) float f32x4;

__device__ __forceinline__ float bf_lo(uint32_t u) { return __uint_as_float(u << 16); }
__device__ __forceinline__ float bf_hi(uint32_t u) { return __uint_as_float(u & 0xffff0000u); }

__device__ __forceinline__ short bfbits(float f) {
    __hip_bfloat16 h = __float2bfloat16(f);
    return *reinterpret_cast<short*>(&h);
}
__device__ __forceinline__ float bffloat(short s) {
    __hip_bfloat16 h = *reinterpret_cast<__hip_bfloat16*>(&s);
    return __bfloat162float(h);
}
__device__ __forceinline__ uint32_t pack_bf2(float a, float b) {
    uint16_t ua = (uint16_t)bfbits(a);
    uint16_t ub = (uint16_t)bfbits(b);
    return (uint32_t)ua | ((uint32_t)ub << 16);
}

// Precompute W fragments (bf16 hi/lo, MFMA A-layout, zero-padded rows) + padded bias.
// wfrag[((t*2+h)*2+s)*64 + lane] = 8 bf16: W[t*16 + (lane&15)][h*32 + (lane>>4)*8 + 0..7]
__global__ void k_prep(const float* __restrict__ w, const float* __restrict__ b,
                       uint4* __restrict__ wfrag, float* __restrict__ b_pad)
{
    const int tid = threadIdx.x;
    if (tid < KP) b_pad[tid] = (tid < KC) ? b[tid] : -1e30f;
    if (tid < 64) {
        const int r16 = tid & 15, gg = tid >> 4;
        for (int t = 0; t < KT; ++t) {
            const int k = t * 16 + r16;
            for (int h = 0; h < 2; ++h) {
                short hi8[8], lo8[8];
                for (int j = 0; j < 8; ++j) {
                    const int c = h * 32 + gg * 8 + j;
                    float v = (k < KC) ? w[k * CD + c] : 0.f;
                    short hb = bfbits(v);
                    hi8[j] = hb;
                    lo8[j] = bfbits(v - bffloat(hb));
                }
                wfrag[((t * 2 + h) * 2 + 0) * 64 + tid] = *reinterpret_cast<uint4*>(hi8);
                wfrag[((t * 2 + h) * 2 + 1) * 64 + tid] = *reinterpret_cast<uint4*>(lo8);
            }
        }
    }
}

// K1: MFMA logits (split-precision bf16) + fused softmax -> a bf16 [nn][l][KP]
// Block: 256 thr (4 waves), 64 l's per block; wave w owns l-tile w*16..w*16+15, all 7 k-tiles.
__global__ __launch_bounds__(256, 4) void k_assign(
    const float* __restrict__ x, const uint4* __restrict__ wfrag,
    const float* __restrict__ b_pad, __hip_bfloat16* __restrict__ a_t, int n0)
{
    __shared__ float xs[CD][65];                       // [c][l] pad-> conflict-free b32
    __shared__ float rns[4][64];
    __shared__ float rn_s[64];
    __shared__ __align__(16) __hip_bfloat16 at[64][136]; // a transpose staging [l][k]

    const int tid = threadIdx.x;
    const int nn  = blockIdx.x >> 6;
    const int lb  = (blockIdx.x & 63) << 6;
    const int n   = n0 + nn;

    // stage x tile [64c][64l], coalesced float4
    const float* xb = x + (size_t)n * CD * LD + lb;
#pragma unroll
    for (int i = 0; i < 4; ++i) {
        int idx = tid + i * 256;                        // 0..1023
        int c = idx >> 4, lq = idx & 15;
        float4 v = *reinterpret_cast<const float4*>(xb + (size_t)c * LD + lq * 4);
        xs[c][lq * 4 + 0] = v.x; xs[c][lq * 4 + 1] = v.y;
        xs[c][lq * 4 + 2] = v.z; xs[c][lq * 4 + 3] = v.w;
    }
    __syncthreads();

    {   // per-l sumsq partials (4 c-quarters x 64 l)
        int l = tid & 63, cq = tid >> 6;
        float ss = 0.f;
#pragma unroll
        for (int j = 0; j < 16; ++j) { float v = xs[cq * 16 + j][l]; ss = fmaf(v, v, ss); }
        rns[cq][l] = ss;
    }
    __syncthreads();
    if (tid < 64) {
        float s = rns[0][tid] + rns[1][tid] + rns[2][tid] + rns[3][tid];
        rn_s[tid] = 1.0f / fmaxf(sqrtf(s), 1e-12f);
    }
    // (rn_s consumed only after the post-MFMA barrier)

    const int lane = tid & 63;
    const int wv   = tid >> 6;
    const int lloc = lane & 15;
    const int g    = lane >> 4;

    // B fragments: x column hi/lo, B-layout: col=lane&15 (l), k=c=(lane>>4)*8+j (+32h)
    bf16x8 bhi0, bhi1, blo0, blo1;
#pragma unroll
    for (int j = 0; j < 8; ++j) {
        float v0 = xs[g * 8 + j][wv * 16 + lloc];
        short h0 = bfbits(v0);
        bhi0[j] = h0; blo0[j] = bfbits(v0 - bffloat(h0));
        float v1 = xs[32 + g * 8 + j][wv * 16 + lloc];
        short h1 = bfbits(v1);
        bhi1[j] = h1; blo1[j] = bfbits(v1 - bffloat(h1));
    }

    f32x4 acc[KT];
#pragma unroll
    for (int t = 0; t < KT; ++t) acc[t] = (f32x4){0.f, 0.f, 0.f, 0.f};

    const bf16x8* wfp = reinterpret_cast<const bf16x8*>(wfrag);
#pragma unroll
    for (int t = 0; t < KT; ++t) {
        bf16x8 wh0 = wfp[((t * 2 + 0) * 2 + 0) * 64 + lane];
        bf16x8 wl0 = wfp[((t * 2 + 0) * 2 + 1) * 64 + lane];
        bf16x8 wh1 = wfp[((t * 2 + 1) * 2 + 0) * 64 + lane];
        bf16x8 wl1 = wfp[((t * 2 + 1) * 2 + 1) * 64 + lane];
        acc[t] = __builtin_amdgcn_mfma_f32_16x16x32_bf16(wh0, bhi0, acc[t], 0, 0, 0);
        acc[t] = __builtin_amdgcn_mfma_f32_16x16x32_bf16(wh1, bhi1, acc[t], 0, 0, 0);
        acc[t] = __builtin_amdgcn_mfma_f32_16x16x32_bf16(wh0, blo0, acc[t], 0, 0, 0);
        acc[t] = __builtin_amdgcn_mfma_f32_16x16x32_bf16(wh1, blo1, acc[t], 0, 0, 0);
        acc[t] = __builtin_amdgcn_mfma_f32_16x16x32_bf16(wl0, bhi0, acc[t], 0, 0, 0);
        acc[t] = __builtin_amdgcn_mfma_f32_16x16x32_bf16(wl1, bhi1, acc[t], 0, 0, 0);
    }
    __syncthreads();   // rn_s ready; xs dead

    // logits -> softmax (per l over k). D-layout: col(l)=lane&15, row(k)=(lane>>4)*4+reg
    const float rn = rn_s[wv * 16 + lloc];
    const float4* bp4 = reinterpret_cast<const float4*>(b_pad);
    float lg[KT][4];
    float m = -3.0e38f;
#pragma unroll
    for (int t = 0; t < KT; ++t) {
        float4 bt = bp4[t * 4 + g];
        lg[t][0] = fmaf(acc[t][0], rn, bt.x);
        lg[t][1] = fmaf(acc[t][1], rn, bt.y);
        lg[t][2] = fmaf(acc[t][2], rn, bt.z);
        lg[t][3] = fmaf(acc[t][3], rn, bt.w);
        m = fmaxf(m, fmaxf(fmaxf(lg[t][0], lg[t][1]), fmaxf(lg[t][2], lg[t][3])));
    }
    m = fmaxf(m, __shfl_xor(m, 16));
    m = fmaxf(m, __shfl_xor(m, 32));
    float s = 0.f;
#pragma unroll
    for (int t = 0; t < KT; ++t) {
#pragma unroll
        for (int r = 0; r < 4; ++r) {
            float e = __expf(lg[t][r] - m);
            lg[t][r] = e;
            s += e;
        }
    }
    s += __shfl_xor(s, 16);
    s += __shfl_xor(s, 32);
    const float inv = 1.0f / s;

    const int lw = wv * 16 + lloc;
#pragma unroll
    for (int t = 0; t < KT; ++t) {
        uint2 pk;
        pk.x = pack_bf2(lg[t][0] * inv, lg[t][1] * inv);
        pk.y = pack_bf2(lg[t][2] * inv, lg[t][3] * inv);
        *reinterpret_cast<uint2*>(&at[lw][t * 16 + g * 4]) = pk;
    }
    {   // zero k=112..127 padding
        uint2 z; z.x = 0u; z.y = 0u;
        *reinterpret_cast<uint2*>(&at[lw][112 + g * 4]) = z;
    }
    __syncthreads();

    // coalesced write-out: [64 l][128 k] bf16 = 16 KB contiguous per block
    __hip_bfloat16* ab = a_t + ((size_t)nn * LD + lb) * KP;
#pragma unroll
    for (int j = 0; j < 4; ++j) {
        int l  = j * 16 + (tid >> 4);
        int ko = (tid & 15) * 8;
        uint4 v = *reinterpret_cast<const uint4*>(&at[l][ko]);
        *reinterpret_cast<uint4*>(ab + (size_t)l * KP + ko) = v;
    }
}

// K2: agg[k,c] partial sums over one eighth of L, per n. 256 thr, 8k x 4c register tile.
__global__ __launch_bounds__(256, 1) void k_agg(
    const float* __restrict__ x, const __hip_bfloat16* __restrict__ a_t,
    float* __restrict__ agg_p, float* __restrict__ asum_p, int n0)
{
    __shared__ float xt[64][68];             // x tile transposed [l][c]
    __shared__ __hip_bfloat16 al[64][KP];    // a tile [l][k]

    const int tid = threadIdx.x;
    const int ls  = blockIdx.x & (LSPLIT - 1);
    const int nn  = blockIdx.x / LSPLIT;
    const int n   = n0 + nn;
    const int kt  = tid >> 4;
    const int ct  = tid & 15;

    float acc[8][4];
#pragma unroll
    for (int i = 0; i < 8; ++i)
#pragma unroll
        for (int j = 0; j < 4; ++j) acc[i][j] = 0.f;
    float asl = 0.f;

    const int lb0 = ls * LS;
    const float* xbase = x + (size_t)n * CD * LD + lb0;
    const uint4* abase = reinterpret_cast<const uint4*>(a_t + ((size_t)nn * LD + lb0) * KP);

    for (int t = 0; t < LS; t += 64) {
#pragma unroll
        for (int i = 0; i < 16; ++i) {
            int idx = tid + (i << 8);
            int cc = idx >> 6, ll = idx & 63;
            xt[ll][cc] = xbase[(size_t)cc * LD + t + ll];
        }
        const uint4* asrc = abase + (size_t)t * (KP / 8);
#pragma unroll
        for (int i = 0; i < 4; ++i)
            reinterpret_cast<uint4*>(&al[0][0])[tid + (i << 8)] = asrc[tid + (i << 8)];
        __syncthreads();

        if (tid < KP) {
#pragma unroll 8
            for (int ll = 0; ll < 64; ++ll) asl += __bfloat162float(al[ll][tid]);
        }

        for (int ll = 0; ll < 64; ++ll) {
            uint4 au = *reinterpret_cast<const uint4*>(&al[ll][kt << 3]);
            float av[8];
            av[0] = bf_lo(au.x); av[1] = bf_hi(au.x);
            av[2] = bf_lo(au.y); av[3] = bf_hi(au.y);
            av[4] = bf_lo(au.z); av[5] = bf_hi(au.z);
            av[6] = bf_lo(au.w); av[7] = bf_hi(au.w);
            float4 xv4 = *reinterpret_cast<const float4*>(&xt[ll][ct << 2]);
            float xs0 = xv4.x, xs1 = xv4.y, xs2 = xv4.z, xs3 = xv4.w;
#pragma unroll
            for (int i = 0; i < 8; ++i) {
                acc[i][0] = fmaf(av[i], xs0, acc[i][0]);
                acc[i][1] = fmaf(av[i], xs1, acc[i][1]);
                acc[i][2] = fmaf(av[i], xs2, acc[i][2]);
                acc[i][3] = fmaf(av[i], xs3, acc[i][3]);
            }
        }
        __syncthreads();
    }

    float* op = agg_p + (((size_t)nn * LSPLIT + ls) * KP + (kt << 3)) * 64 + (ct << 2);
#pragma unroll
    for (int i = 0; i < 8; ++i) {
        float4 v; v.x = acc[i][0]; v.y = acc[i][1]; v.z = acc[i][2]; v.w = acc[i][3];
        *reinterpret_cast<float4*>(op + (size_t)i * 64) = v;
    }
    if (tid < KP) asum_p[((size_t)nn * LSPLIT + ls) * KP + tid] = asl;
}

// K3: reduce partials, subtract centroid*asum, intra-norm over C, global L2 norm.
__global__ __launch_bounds__(256, 1) void k_final(
    const float* __restrict__ agg_p, const float* __restrict__ asum_p,
    const float* __restrict__ cent, float* __restrict__ out, int n0)
{
    __shared__ float vbuf[KC][65];
    __shared__ float asum_s[KP];
    __shared__ float rn_s[KC];
    __shared__ float red[256];

    const int tid = threadIdx.x;
    const int nn  = blockIdx.x;
    const int n   = n0 + nn;

    if (tid < KP) {
        float s = 0.f;
#pragma unroll
        for (int ls = 0; ls < LSPLIT; ++ls)
            s += asum_p[((size_t)nn * LSPLIT + ls) * KP + tid];
        asum_s[tid] = s;
    }
    __syncthreads();

    for (int idx = tid; idx < KC * CD; idx += 256) {
        int k = idx >> 6, c = idx & 63;
        float s = 0.f;
#pragma unroll
        for (int ls = 0; ls < LSPLIT; ++ls)
            s += agg_p[(((size_t)nn * LSPLIT + ls) * KP + k) * 64 + c];
        vbuf[k][c] = fmaf(-cent[idx], asum_s[k], s);
    }
    __syncthreads();

    if (tid < KC) {
        float ssq = 0.f;
#pragma unroll 8
        for (int c = 0; c < CD; ++c) {
            float v = vbuf[tid][c];
            ssq = fmaf(v, v, ssq);
        }
        rn_s[tid] = 1.0f / fmaxf(sqrtf(ssq), 1e-12f);
    }
    __syncthreads();

    float gp = 0.f;
    for (int idx = tid; idx < KC * CD; idx += 256) {
        int k = idx >> 6, c = idx & 63;
        float v = vbuf[k][c] * rn_s[k];
        gp = fmaf(v, v, gp);
    }
    red[tid] = gp;
    __syncthreads();
    for (int off = 128; off > 0; off >>= 1) {
        if (tid < off) red[tid] += red[tid + off];
        __syncthreads();
    }
    const float g = 1.0f / fmaxf(sqrtf(red[0]), 1e-12f);

    float* op = out + (size_t)n * (KC * CD);
    for (int idx = tid; idx < KC * CD; idx += 256) {
        int k = idx >> 6, c = idx & 63;
        op[idx] = vbuf[k][c] * rn_s[k] * g;
    }
}

extern "C" void kernel_launch(void* const* d_in, const int* in_sizes, int n_in,
                              void* d_out, int out_size, void* d_ws, size_t ws_size,
                              hipStream_t stream)
{
    const float* x  = (const float*)d_in[0];
    const float* w  = (const float*)d_in[1];
    const float* b  = (const float*)d_in[2];
    const float* ct = (const float*)d_in[3];
    float* out = (float*)d_out;

    char* wsp = (char*)d_ws;
    uint4* wfrag = (uint4*)wsp;                 // 28672 B (7*2*2*64 frags * 16B)
    float* b_pad = (float*)(wsp + 28672);       // 512 B
    char* chunk  = wsp + 32768;

    const size_t a_per_n    = (size_t)LD * KP * 2;          // bf16 assignments
    const size_t agg_per_n  = (size_t)LSPLIT * KP * 64 * 4; // fp32 agg partials
    const size_t asum_per_n = (size_t)LSPLIT * KP * 4;      // fp32 asum partials
    const size_t per_n = a_per_n + agg_per_n + asum_per_n;

    size_t avail = ws_size > 32768 ? ws_size - 32768 : 0;
    int nc = (int)(avail / per_n);
    if (nc < 1) nc = 1;
    if (nc > NB) nc = NB;

    __hip_bfloat16* a_t = (__hip_bfloat16*)chunk;
    float* agg_p  = (float*)(chunk + a_per_n * (size_t)nc);
    float* asum_p = (float*)(chunk + (a_per_n + agg_per_n) * (size_t)nc);

    k_prep<<<1, 128, 0, stream>>>(w, b, wfrag, b_pad);
    for (int n0 = 0; n0 < NB; n0 += nc) {
        int cn = NB - n0; if (cn > nc) cn = nc;
        k_assign<<<cn * 64, 256, 0, stream>>>(x, wfrag, b_pad, a_t, n0);
        k_agg<<<cn * LSPLIT, 256, 0, stream>>>(x, a_t, agg_p, asum_p, n0);
        k_final<<<cn, 256, 0, stream>>>(agg_p, asum_p, ct, out, n0);
    }
}

// Round 4
// 98.236 us; speedup vs baseline: 6.8486x; 2.2099x over previous
//
#include <hip/hip_runtime.h>
#include <hip/hip_bf16.h>
#include <cstdint>

#define NB   128
#define CD   64
#define LD   4096
#define KC   100
#define KT   7            // 7 k-tiles of 16 -> 112 padded clusters
#define KR   (KT * 16)    // 112
#define AKP  72           // akl row stride: 144 B rows, keeps b128 reads 16B-aligned
#define LSPLIT 8
#define LCH  (LD / LSPLIT) // 512 l's per block
#define ITERS (LCH / 64)   // 8 inner iters of 64 l

typedef __attribute__((ext_vector_type(8))) short bf16x8;
typedef __attribute__((ext_vector_type(4))) float f32x4;

__device__ __forceinline__ short bfbits(float f) {
    __hip_bfloat16 h = __float2bfloat16(f);
    return *reinterpret_cast<short*>(&h);
}
__device__ __forceinline__ float bffloat(short s) {
    __hip_bfloat16 h = *reinterpret_cast<__hip_bfloat16*>(&s);
    return __bfloat162float(h);
}

// Precompute W fragments (bf16 hi/lo, MFMA A-layout, zero-padded rows) + padded bias.
// wfrag[((t*2+h)*2+s)*64 + lane] = 8 bf16: W[t*16 + (lane&15)][h*32 + (lane>>4)*8 + 0..7]
__global__ void k_prep(const float* __restrict__ w, const float* __restrict__ b,
                       uint4* __restrict__ wfrag, float* __restrict__ b_pad)
{
    const int tid = threadIdx.x;
    if (tid < 128) b_pad[tid] = (tid < KC) ? b[tid] : -1e30f;
    if (tid < 64) {
        const int r16 = tid & 15, gg = tid >> 4;
        for (int t = 0; t < KT; ++t) {
            const int k = t * 16 + r16;
            for (int h = 0; h < 2; ++h) {
                short hi8[8], lo8[8];
                for (int j = 0; j < 8; ++j) {
                    const int c = h * 32 + gg * 8 + j;
                    float v = (k < KC) ? w[k * CD + c] : 0.f;
                    short hb = bfbits(v);
                    hi8[j] = hb;
                    lo8[j] = bfbits(v - bffloat(hb));
                }
                wfrag[((t * 2 + h) * 2 + 0) * 64 + tid] = *reinterpret_cast<uint4*>(hi8);
                wfrag[((t * 2 + h) * 2 + 1) * 64 + tid] = *reinterpret_cast<uint4*>(lo8);
            }
        }
    }
}

// Fused: normalize+logits (MFMA) + softmax + agg (MFMA) + asum (LDS row-sum).
// Block: 256 thr (4 waves). Grid: cn * LSPLIT. Each block: one n, 512 l's, 8 iters of 64.
__global__ __launch_bounds__(256, 2) void k_fused(
    const float* __restrict__ x, const uint4* __restrict__ wfrag,
    const float* __restrict__ b_pad,
    float* __restrict__ agg_pT, float* __restrict__ asum_pT, int n0)
{
    __shared__ float xs[CD][65];                          // x tile [c][l], fp32
    __shared__ __align__(16) __hip_bfloat16 akl[KR][AKP]; // a tile [k][l], plain indexing
    __shared__ __align__(16) uint4 wlds[KT * 2 * 2 * 64]; // W fragments

    const int tid  = threadIdx.x;
    const int lane = tid & 63;
    const int wv   = tid >> 6;
    const int lloc = lane & 15;
    const int g    = lane >> 4;

    // one-time: W fragments -> LDS (28672 B); first read is after S1 of iter 0
    for (int i = tid; i < KT * 2 * 2 * 64; i += 256) wlds[i] = wfrag[i];

    const int nn = blockIdx.x >> 3;
    const int ls = blockIdx.x & 7;
    const int n  = n0 + nn;
    const float* xb = x + (size_t)n * CD * LD + ls * LCH;

    // bias preload (this lane's 4 k's per tile)
    const float4* bp4 = reinterpret_cast<const float4*>(b_pad);
    float4 bv[KT];
#pragma unroll
    for (int t = 0; t < KT; ++t) bv[t] = bp4[t * 4 + g];

    f32x4 aagg[KT];
#pragma unroll
    for (int mt = 0; mt < KT; ++mt) aagg[mt] = (f32x4){0.f, 0.f, 0.f, 0.f};
    float asl = 0.f;   // asum accumulator (threads tid<KR own row k=tid)

    // prefetch iter 0's x tile into regs
    float4 pv[4];
#pragma unroll
    for (int i = 0; i < 4; ++i) {
        int idx = tid + i * 256, c = idx >> 4, lq = idx & 15;
        pv[i] = *reinterpret_cast<const float4*>(xb + (size_t)c * LD + lq * 4);
    }

    const bf16x8* wfp = reinterpret_cast<const bf16x8*>(wlds);
    const int lw = wv * 16 + lloc;    // this lane's l (logits/softmax phase)
    const int cb = wv * 16 + lloc;    // this lane's c (agg phase)

    for (int it = 0; it < ITERS; ++it) {
        __syncthreads();                               // S0: xs/akl free
        // write staged x tile
#pragma unroll
        for (int i = 0; i < 4; ++i) {
            int idx = tid + i * 256, c = idx >> 4, lq = idx & 15;
            xs[c][lq * 4 + 0] = pv[i].x; xs[c][lq * 4 + 1] = pv[i].y;
            xs[c][lq * 4 + 2] = pv[i].z; xs[c][lq * 4 + 3] = pv[i].w;
        }
        __syncthreads();                               // S1: xs (and wlds) ready

        // logits B-frags (x column hi/lo) + sumsq-over-c via shfl
        float ss = 0.f;
        bf16x8 bhi0, blo0, bhi1, blo1;
#pragma unroll
        for (int j = 0; j < 8; ++j) {
            float v0 = xs[g * 8 + j][lw];
            ss = fmaf(v0, v0, ss);
            short h0 = bfbits(v0);
            bhi0[j] = h0; blo0[j] = bfbits(v0 - bffloat(h0));
            float v1 = xs[32 + g * 8 + j][lw];
            ss = fmaf(v1, v1, ss);
            short h1 = bfbits(v1);
            bhi1[j] = h1; blo1[j] = bfbits(v1 - bffloat(h1));
        }
        ss += __shfl_xor(ss, 16);
        ss += __shfl_xor(ss, 32);
        const float rn = 1.0f / fmaxf(sqrtf(ss), 1e-12f);

        // logits MFMA (split precision: hh + hl + lh)
        f32x4 acc[KT];
#pragma unroll
        for (int t = 0; t < KT; ++t) acc[t] = (f32x4){0.f, 0.f, 0.f, 0.f};
#pragma unroll
        for (int t = 0; t < KT; ++t) {
            bf16x8 wh0 = wfp[((t * 2 + 0) * 2 + 0) * 64 + lane];
            bf16x8 wl0 = wfp[((t * 2 + 0) * 2 + 1) * 64 + lane];
            bf16x8 wh1 = wfp[((t * 2 + 1) * 2 + 0) * 64 + lane];
            bf16x8 wl1 = wfp[((t * 2 + 1) * 2 + 1) * 64 + lane];
            acc[t] = __builtin_amdgcn_mfma_f32_16x16x32_bf16(wh0, bhi0, acc[t], 0, 0, 0);
            acc[t] = __builtin_amdgcn_mfma_f32_16x16x32_bf16(wh1, bhi1, acc[t], 0, 0, 0);
            acc[t] = __builtin_amdgcn_mfma_f32_16x16x32_bf16(wh0, blo0, acc[t], 0, 0, 0);
            acc[t] = __builtin_amdgcn_mfma_f32_16x16x32_bf16(wh1, blo1, acc[t], 0, 0, 0);
            acc[t] = __builtin_amdgcn_mfma_f32_16x16x32_bf16(wl0, bhi0, acc[t], 0, 0, 0);
            acc[t] = __builtin_amdgcn_mfma_f32_16x16x32_bf16(wl1, bhi1, acc[t], 0, 0, 0);
        }

        // softmax over k (per l). D: col(l)=lane&15, row(k)=g*4+r (+16t)
        float m = -3.0e38f;
#pragma unroll
        for (int t = 0; t < KT; ++t) {
            acc[t][0] = fmaf(acc[t][0], rn, bv[t].x);
            acc[t][1] = fmaf(acc[t][1], rn, bv[t].y);
            acc[t][2] = fmaf(acc[t][2], rn, bv[t].z);
            acc[t][3] = fmaf(acc[t][3], rn, bv[t].w);
            m = fmaxf(m, fmaxf(fmaxf(acc[t][0], acc[t][1]), fmaxf(acc[t][2], acc[t][3])));
        }
        m = fmaxf(m, __shfl_xor(m, 16));
        m = fmaxf(m, __shfl_xor(m, 32));
        float s = 0.f;
#pragma unroll
        for (int t = 0; t < KT; ++t) {
#pragma unroll
            for (int r = 0; r < 4; ++r) {
                float e = __expf(acc[t][r] - m);
                acc[t][r] = e;
                s += e;
            }
        }
        s += __shfl_xor(s, 16);
        s += __shfl_xor(s, 32);
        const float inv = 1.0f / s;

        // a -> LDS [k][l] bf16, plain indexing
#pragma unroll
        for (int r = 0; r < 4; ++r) {
#pragma unroll
            for (int t = 0; t < KT; ++t)
                akl[t * 16 + g * 4 + r][lw] = __float2bfloat16(acc[t][r] * inv);
        }

        // prefetch next iter's x during the MFMA-heavy agg phase
        if (it + 1 < ITERS) {
#pragma unroll
            for (int i = 0; i < 4; ++i) {
                int idx = tid + i * 256, c = idx >> 4, lq = idx & 15;
                pv[i] = *reinterpret_cast<const float4*>(
                    xb + (it + 1) * 64 + (size_t)c * LD + lq * 4);
            }
        }
        __syncthreads();                               // S3: akl ready

        // asum: thread tid<112 sums its row k=tid over this tile's 64 l's
        if (tid < KR) {
            const bf16x8* rp = reinterpret_cast<const bf16x8*>(&akl[tid][0]);
            float rs = 0.f;
#pragma unroll
            for (int q = 0; q < 8; ++q) {
                bf16x8 v = rp[q];
#pragma unroll
                for (int j = 0; j < 8; ++j) rs += bffloat(v[j]);
            }
            asl += rs;
        }

        // agg MFMA: A = a frags (k rows), B = x hi/lo (c cols), redn = l
#pragma unroll
        for (int h = 0; h < 2; ++h) {
            const float* xrow = &xs[cb][h * 32 + g * 8];
            bf16x8 xh, xl;
#pragma unroll
            for (int j = 0; j < 8; ++j) {
                float v = xrow[j];
                short hb = bfbits(v);
                xh[j] = hb; xl[j] = bfbits(v - bffloat(hb));
            }
#pragma unroll
            for (int mt = 0; mt < KT; ++mt) {
                bf16x8 af = *reinterpret_cast<const bf16x8*>(
                    &akl[mt * 16 + lloc][h * 32 + g * 8]);
                aagg[mt] = __builtin_amdgcn_mfma_f32_16x16x32_bf16(af, xh, aagg[mt], 0, 0, 0);
                aagg[mt] = __builtin_amdgcn_mfma_f32_16x16x32_bf16(af, xl, aagg[mt], 0, 0, 0);
            }
        }
    }

    // write partials: agg_pT[nls][c][128kpad], asum_pT[nls][112]
    const size_t nls = (size_t)nn * LSPLIT + ls;
    float* ap = agg_pT + (nls * 64 + cb) * 128 + g * 4;
#pragma unroll
    for (int mt = 0; mt < KT; ++mt)
        *reinterpret_cast<f32x4*>(ap + mt * 16) = aagg[mt];
    if (tid < KR) asum_pT[nls * KR + tid] = asl;
}

// Final: reduce partials, subtract centroid*asum, intra-norm over C, global L2 norm.
__global__ __launch_bounds__(256, 1) void k_final(
    const float* __restrict__ agg_pT, const float* __restrict__ asum_pT,
    const float* __restrict__ cent, float* __restrict__ out, int n0)
{
    __shared__ float vbuf[KC][65];
    __shared__ float asum_s[KR];
    __shared__ float rn_s[KC];
    __shared__ float red[256];

    const int tid = threadIdx.x;
    const int nn  = blockIdx.x;
    const int n   = n0 + nn;
    const size_t nb8 = (size_t)nn * LSPLIT;

    if (tid < KR) {
        float s = 0.f;
#pragma unroll
        for (int ls = 0; ls < LSPLIT; ++ls)
            s += asum_pT[(nb8 + ls) * KR + tid];
        asum_s[tid] = s;
    }
    __syncthreads();

    for (int idx = tid; idx < 64 * 128; idx += 256) {
        int c = idx >> 7, k = idx & 127;
        if (k < KC) {
            float s = 0.f;
#pragma unroll
            for (int ls = 0; ls < LSPLIT; ++ls)
                s += agg_pT[((nb8 + ls) * 64 + c) * 128 + k];
            vbuf[k][c] = fmaf(-cent[k * CD + c], asum_s[k], s);
        }
    }
    __syncthreads();

    if (tid < KC) {
        float ssq = 0.f;
#pragma unroll 8
        for (int c = 0; c < CD; ++c) {
            float v = vbuf[tid][c];
            ssq = fmaf(v, v, ssq);
        }
        rn_s[tid] = 1.0f / fmaxf(sqrtf(ssq), 1e-12f);
    }
    __syncthreads();

    float gp = 0.f;
    for (int idx = tid; idx < KC * CD; idx += 256) {
        int k = idx >> 6, c = idx & 63;
        float v = vbuf[k][c] * rn_s[k];
        gp = fmaf(v, v, gp);
    }
    red[tid] = gp;
    __syncthreads();
    for (int off = 128; off > 0; off >>= 1) {
        if (tid < off) red[tid] += red[tid + off];
        __syncthreads();
    }
    const float gnorm = 1.0f / fmaxf(sqrtf(red[0]), 1e-12f);

    float* op = out + (size_t)n * (KC * CD);
    for (int idx = tid; idx < KC * CD; idx += 256) {
        int k = idx >> 6, c = idx & 63;
        op[idx] = vbuf[k][c] * rn_s[k] * gnorm;
    }
}

extern "C" void kernel_launch(void* const* d_in, const int* in_sizes, int n_in,
                              void* d_out, int out_size, void* d_ws, size_t ws_size,
                              hipStream_t stream)
{
    const float* x  = (const float*)d_in[0];
    const float* w  = (const float*)d_in[1];
    const float* b  = (const float*)d_in[2];
    const float* ct = (const float*)d_in[3];
    float* out = (float*)d_out;

    char* wsp = (char*)d_ws;
    uint4* wfrag = (uint4*)wsp;                 // 28672 B
    float* b_pad = (float*)(wsp + 28672);       // 512 B
    char* chunk  = wsp + 32768;

    const size_t agg_per_n  = (size_t)LSPLIT * 64 * 128 * 4; // 262144 B
    const size_t asum_per_n = (size_t)LSPLIT * KR * 4;       // 3584 B
    const size_t per_n = agg_per_n + asum_per_n;

    size_t avail = ws_size > 32768 ? ws_size - 32768 : 0;
    int nc = (int)(avail / per_n);
    if (nc < 1) nc = 1;
    if (nc > NB) nc = NB;

    float* agg_pT  = (float*)chunk;
    float* asum_pT = (float*)(chunk + agg_per_n * (size_t)nc);

    k_prep<<<1, 128, 0, stream>>>(w, b, wfrag, b_pad);
    for (int n0 = 0; n0 < NB; n0 += nc) {
        int cn = NB - n0; if (cn > nc) cn = nc;
        k_fused<<<cn * LSPLIT, 256, 0, stream>>>(x, wfrag, b_pad, agg_pT, asum_pT, n0);
        k_final<<<cn, 256, 0, stream>>>(agg_pT, asum_pT, ct, out, n0);
    }
}